// Round 1
// baseline (294.404 us; speedup 1.0000x reference)
//
#include <hip/hip_runtime.h>

// ---------------------------------------------------------------------------
// TransformerDecoderBlockV2: bf16 MFMA implementation for gfx950
// B=1, N=2048, M=2048, D=1024, H=16, dh=64, DFF=4096
// ---------------------------------------------------------------------------

using bf16x8 = __attribute__((ext_vector_type(8))) short;
using f32x4  = __attribute__((ext_vector_type(4))) float;

__device__ __forceinline__ ushort f2bf(float f) {
    unsigned u = __float_as_uint(f);
    unsigned r = (u + 0x7fffu + ((u >> 16) & 1u)) >> 16;
    return (ushort)r;
}

__device__ __forceinline__ void gload16(const void* g, void* l) {
    __builtin_amdgcn_global_load_lds(
        (const __attribute__((address_space(1))) void*)g,
        (__attribute__((address_space(3))) void*)l, 16, 0, 0);
}

__device__ __forceinline__ float gelu_erf(float v) {
    return 0.5f * v * (1.0f + erff(v * 0.70710678118654752f));
}

// ---------------------------------------------------------------------------
// f32 -> bf16 elementwise convert (vectorized, 4/thread)
// ---------------------------------------------------------------------------
__global__ __launch_bounds__(256) void cvt4(const float* __restrict__ in,
                                            ushort* __restrict__ out, int n) {
    int i = (blockIdx.x * 256 + threadIdx.x) * 4;
    if (i + 3 < n) {
        float4 v = *(const float4*)(in + i);
        ushort4 o;
        o.x = f2bf(v.x); o.y = f2bf(v.y); o.z = f2bf(v.z); o.w = f2bf(v.w);
        *(ushort4*)(out + i) = o;
    }
}

// ---------------------------------------------------------------------------
// Transpose + convert: in f32 [R][C]  ->  out bf16 [C][R]
// block (32,8), tile 32x32
// ---------------------------------------------------------------------------
__global__ __launch_bounds__(256) void tcvt(const float* __restrict__ in,
                                            ushort* __restrict__ out, int R, int C) {
    __shared__ float tile[32][33];
    const int tx = threadIdx.x, ty = threadIdx.y;
    const int c0 = blockIdx.x * 32, r0 = blockIdx.y * 32;
#pragma unroll
    for (int i = 0; i < 4; ++i)
        tile[ty + 8 * i][tx] = in[(size_t)(r0 + ty + 8 * i) * C + c0 + tx];
    __syncthreads();
#pragma unroll
    for (int i = 0; i < 4; ++i)
        out[(size_t)(c0 + ty + 8 * i) * R + r0 + tx] = f2bf(tile[tx][ty + 8 * i]);
}

// ---------------------------------------------------------------------------
// V transpose: KV bf16 [4096][2048] (V = cols 1024..2047) -> Vt bf16 [1024][4096]
// ---------------------------------------------------------------------------
__global__ __launch_bounds__(256) void vtrans(const ushort* __restrict__ KV,
                                              ushort* __restrict__ Vt) {
    __shared__ ushort tile[32][34];
    const int tx = threadIdx.x, ty = threadIdx.y;
    const int j0 = blockIdx.x * 32, d0 = blockIdx.y * 32;
#pragma unroll
    for (int i = 0; i < 4; ++i)
        tile[ty + 8 * i][tx] = KV[(size_t)(j0 + ty + 8 * i) * 2048 + 1024 + d0 + tx];
    __syncthreads();
#pragma unroll
    for (int i = 0; i < 4; ++i)
        Vt[(size_t)(d0 + ty + 8 * i) * 4096 + j0 + tx] = tile[tx][ty + 8 * i];
}

// ---------------------------------------------------------------------------
// GEMM: C[M][N] = epilogue( A[M][K]_bf16 * Bt[N][K]_bf16^T + bias )
// 4 waves in 2x2 grid over BMxBN tile, BK=64, 16x16x32 bf16 MFMA.
// LDS tiles XOR-swizzled (T2): LDS[r][cb^((r&7)<<4)] holds global [r][cb].
// Staged via global_load_lds width 16 with pre-swizzled global source.
// ---------------------------------------------------------------------------
template <int BM, int BN, int ACT, int OUTF32, int RES, int SCALED>
__global__ __launch_bounds__(256) void gemm_bt(
    const ushort* __restrict__ A, const ushort* __restrict__ Bt,
    const float* __restrict__ bias, const float* __restrict__ resid,
    void* __restrict__ Cout, int M, int N, int K, float scale) {
    constexpr int MR = BM / 32, NR = BN / 32;
    __shared__ __align__(16) ushort Asm[BM * 64];
    __shared__ __align__(16) ushort Bsm[BN * 64];
    const int tid = threadIdx.x;
    const int w = tid >> 6, lane = tid & 63, g = lane >> 4, i15 = lane & 15;
    const int wm = w >> 1, wn = w & 1;
    const int m0 = blockIdx.y * BM, n0 = blockIdx.x * BN;

    f32x4 acc[MR][NR] = {};

    for (int kt = 0; kt < K; kt += 64) {
        // stage A tile (BM x 64 bf16 = BM*128 bytes)
#pragma unroll
        for (int q = 0; q < BM / 32; ++q) {
            int off = (w * (BM / 32) + q) * 1024 + lane * 16;
            int r = off >> 7, cb = off & 127;
            int scb = cb ^ ((r & 7) << 4);
            const void* src = (const char*)A + ((size_t)(m0 + r) * K + kt) * 2 + scb;
            gload16(src, (char*)Asm + (w * (BM / 32) + q) * 1024);
        }
        // stage B tile (BN x 64)
#pragma unroll
        for (int q = 0; q < BN / 32; ++q) {
            int off = (w * (BN / 32) + q) * 1024 + lane * 16;
            int r = off >> 7, cb = off & 127;
            int scb = cb ^ ((r & 7) << 4);
            const void* src = (const char*)Bt + ((size_t)(n0 + r) * K + kt) * 2 + scb;
            gload16(src, (char*)Bsm + (w * (BN / 32) + q) * 1024);
        }
        __syncthreads();

#pragma unroll
        for (int kc = 0; kc < 2; ++kc) {
            bf16x8 af[MR], bfr[NR];
#pragma unroll
            for (int mi = 0; mi < MR; ++mi) {
                int r = wm * (BM / 2) + mi * 16 + i15;
                af[mi] = *(const bf16x8*)((const char*)Asm + r * 128 +
                                          ((kc * 64 + g * 16) ^ ((r & 7) << 4)));
            }
#pragma unroll
            for (int ni = 0; ni < NR; ++ni) {
                int r = wn * (BN / 2) + ni * 16 + i15;
                bfr[ni] = *(const bf16x8*)((const char*)Bsm + r * 128 +
                                           ((kc * 64 + g * 16) ^ ((r & 7) << 4)));
            }
#pragma unroll
            for (int mi = 0; mi < MR; ++mi)
#pragma unroll
                for (int ni = 0; ni < NR; ++ni)
                    acc[mi][ni] = __builtin_amdgcn_mfma_f32_16x16x32_bf16(
                        af[mi], bfr[ni], acc[mi][ni], 0, 0, 0);
        }
        __syncthreads();
    }

    // epilogue: C/D layout col = lane&15, row = (lane>>4)*4 + reg
#pragma unroll
    for (int ni = 0; ni < NR; ++ni) {
        int col = n0 + wn * (BN / 2) + ni * 16 + i15;
        float bb = bias[col];
#pragma unroll
        for (int mi = 0; mi < MR; ++mi) {
#pragma unroll
            for (int r2 = 0; r2 < 4; ++r2) {
                int row = m0 + wm * (BM / 2) + mi * 16 + 4 * g + r2;
                float v = acc[mi][ni][r2] + bb;
                if (ACT) v = gelu_erf(v);
                if (SCALED) v *= scale;
                size_t off = (size_t)row * N + col;
                if (OUTF32) {
                    float rv = RES ? resid[off] : 0.f;
                    ((float*)Cout)[off] = v + rv;
                } else {
                    ((ushort*)Cout)[off] = f2bf(v);
                }
            }
        }
    }
}

// ---------------------------------------------------------------------------
// Flash attention (swapped-QK^T), 4 waves x 16 q-rows, KVBLK=64.
// Q pre-scaled by dh^-0.5. Causal mask on self part only (cols < N).
// ---------------------------------------------------------------------------
__global__ __launch_bounds__(256) void flash_attn(
    const ushort* __restrict__ Q,    // [2048][1024] bf16 (scaled)
    const ushort* __restrict__ KVb,  // [4096][2048] bf16 (K = cols 0..1023)
    const ushort* __restrict__ Vt,   // [1024][4096] bf16
    ushort* __restrict__ O) {        // [2048][1024] bf16
    constexpr int N = 2048, D = 1024;
    __shared__ __align__(16) ushort Ksm[64 * 64];      // [j][d] swizzled
    __shared__ __align__(16) ushort Vsm[64 * 64];      // [d][j] swizzled
    __shared__ __align__(16) ushort Psm[4][16][72];    // per-wave [i][j], row pad

    const int tid = threadIdx.x;
    const int w = tid >> 6, lane = tid & 63, g = lane >> 4, i15 = lane & 15;
    const int h = blockIdx.y, qb = blockIdx.x * 64;
    const int qrow = qb + w * 16 + i15;

    bf16x8 qf[2];
    qf[0] = *(const bf16x8*)(Q + (size_t)qrow * D + h * 64 + g * 8);
    qf[1] = *(const bf16x8*)(Q + (size_t)qrow * D + h * 64 + 32 + g * 8);

    f32x4 o[4] = {};
    float m_run = -INFINITY, l_run = 0.f;

    const int diag = qb >> 6;
    const int ntiles = diag + 1 + 32;

    for (int t = 0; t < ntiles; ++t) {
        const int jt = (t <= diag) ? t : (32 + (t - diag - 1));
        // stage K tile [64 j][64 d] and Vt tile [64 d][64 j], XOR-swizzled
#pragma unroll
        for (int qq = 0; qq < 2; ++qq) {
            int idx = qq * 256 + tid;
            int r = idx >> 3, cb = (idx & 7) * 16;
            int sw = cb ^ ((r & 7) << 4);
            uint4 kd = *(const uint4*)((const char*)KVb +
                       ((size_t)(jt * 64 + r) * 2048 + h * 64) * 2 + cb);
            *(uint4*)((char*)Ksm + r * 128 + sw) = kd;
            uint4 vd = *(const uint4*)((const char*)Vt +
                       ((size_t)(h * 64 + r) * 4096 + jt * 64) * 2 + cb);
            *(uint4*)((char*)Vsm + r * 128 + sw) = vd;
        }
        __syncthreads();

        // S^T = K * Q^T : frags st[jg], lane holds col i=i15, rows j=jg*16+4g+r
        f32x4 st[4];
#pragma unroll
        for (int jg = 0; jg < 4; ++jg) {
            int jr = jg * 16 + i15;
            bf16x8 ka0 = *(const bf16x8*)((const char*)Ksm + jr * 128 +
                                          ((g * 16) ^ ((jr & 7) << 4)));
            bf16x8 ka1 = *(const bf16x8*)((const char*)Ksm + jr * 128 +
                                          ((64 + g * 16) ^ ((jr & 7) << 4)));
            f32x4 z = {};
            z = __builtin_amdgcn_mfma_f32_16x16x32_bf16(ka0, qf[0], z, 0, 0, 0);
            z = __builtin_amdgcn_mfma_f32_16x16x32_bf16(ka1, qf[1], z, 0, 0, 0);
            st[jg] = z;
        }
        if (jt == diag) {
#pragma unroll
            for (int jg = 0; jg < 4; ++jg)
#pragma unroll
                for (int r = 0; r < 4; ++r) {
                    int j = jt * 64 + jg * 16 + 4 * g + r;
                    if (j > qrow) st[jg][r] = -50000.f;
                }
        }
        // online softmax: row stats for i = i15 (replicated over g after xor)
        float mt = -INFINITY;
#pragma unroll
        for (int jg = 0; jg < 4; ++jg)
#pragma unroll
            for (int r = 0; r < 4; ++r) mt = fmaxf(mt, st[jg][r]);
        mt = fmaxf(mt, __shfl_xor(mt, 16));
        mt = fmaxf(mt, __shfl_xor(mt, 32));
        float mnew = fmaxf(m_run, mt);
        float fscale = __expf(m_run - mnew);
        float psum = 0.f;
        ushort pb[4][4];
#pragma unroll
        for (int jg = 0; jg < 4; ++jg)
#pragma unroll
            for (int r = 0; r < 4; ++r) {
                float p = __expf(st[jg][r] - mnew);
                psum += p;
                pb[jg][r] = f2bf(p);
            }
        psum += __shfl_xor(psum, 16);
        psum += __shfl_xor(psum, 32);
        l_run = l_run * fscale + psum;
        m_run = mnew;

        // rescale O: O-frag rows are i_local = 4g+r; stats live at lanes (l&15)==i_local
#pragma unroll
        for (int r = 0; r < 4; ++r) {
            float fr = __shfl(fscale, 20 * g + r);
#pragma unroll
            for (int dg = 0; dg < 4; ++dg) o[dg][r] *= fr;
        }

        // write P (bf16) to per-wave LDS [16 i][64 j]
#pragma unroll
        for (int jg = 0; jg < 4; ++jg) {
            uint2 pk;
            pk.x = (uint)pb[jg][0] | ((uint)pb[jg][1] << 16);
            pk.y = (uint)pb[jg][2] | ((uint)pb[jg][3] << 16);
            *(uint2*)((char*)&Psm[w][i15][0] + jg * 32 + 8 * g) = pk;
        }
        __syncthreads();

        // O += P * V : A = P rows i, B = Vt cols
#pragma unroll
        for (int jc = 0; jc < 2; ++jc) {
            bf16x8 pa = *(const bf16x8*)((const char*)&Psm[w][i15][0] + jc * 64 + g * 16);
#pragma unroll
            for (int dg = 0; dg < 4; ++dg) {
                int dr = dg * 16 + i15;
                bf16x8 vb = *(const bf16x8*)((const char*)Vsm + dr * 128 +
                                             ((jc * 64 + g * 16) ^ ((dr & 7) << 4)));
                o[dg] = __builtin_amdgcn_mfma_f32_16x16x32_bf16(pa, vb, o[dg], 0, 0, 0);
            }
        }
        __syncthreads();
    }

    // final normalize + write
#pragma unroll
    for (int r = 0; r < 4; ++r) {
        float lr = __shfl(l_run, 20 * g + r);
        float inv = 1.f / lr;
#pragma unroll
        for (int dg = 0; dg < 4; ++dg) {
            int row = qb + w * 16 + 4 * g + r;
            int col = h * 64 + dg * 16 + i15;
            O[(size_t)row * D + col] = f2bf(o[dg][r] * inv);
        }
    }
}

// ---------------------------------------------------------------------------
// LayerNorm over D=1024, one block per row; writes f32 and optional bf16
// ---------------------------------------------------------------------------
__global__ __launch_bounds__(256) void layernorm_k(
    const float* __restrict__ in, const float* __restrict__ gam,
    const float* __restrict__ bet, float* __restrict__ outf,
    ushort* __restrict__ outb) {
    const int row = blockIdx.x, tid = threadIdx.x;
    const float4 v = *(const float4*)(in + (size_t)row * 1024 + tid * 4);
    float s = v.x + v.y + v.z + v.w;
    float sq = v.x * v.x + v.y * v.y + v.z * v.z + v.w * v.w;
#pragma unroll
    for (int d = 1; d < 64; d <<= 1) {
        s += __shfl_xor(s, d);
        sq += __shfl_xor(sq, d);
    }
    __shared__ float red[8];
    const int w = tid >> 6;
    if ((tid & 63) == 0) { red[w] = s; red[4 + w] = sq; }
    __syncthreads();
    s = red[0] + red[1] + red[2] + red[3];
    sq = red[4] + red[5] + red[6] + red[7];
    const float mu = s * (1.f / 1024.f);
    const float rs = rsqrtf(sq * (1.f / 1024.f) - mu * mu + 1e-5f);
    const float4 gg = *(const float4*)(gam + tid * 4);
    const float4 bb = *(const float4*)(bet + tid * 4);
    float4 o;
    o.x = (v.x - mu) * rs * gg.x + bb.x;
    o.y = (v.y - mu) * rs * gg.y + bb.y;
    o.z = (v.z - mu) * rs * gg.z + bb.z;
    o.w = (v.w - mu) * rs * gg.w + bb.w;
    *(float4*)(outf + (size_t)row * 1024 + tid * 4) = o;
    if (outb) {
        ushort4 ob;
        ob.x = f2bf(o.x); ob.y = f2bf(o.y); ob.z = f2bf(o.z); ob.w = f2bf(o.w);
        *(ushort4*)(outb + (size_t)row * 1024 + tid * 4) = ob;
    }
}

// ---------------------------------------------------------------------------
extern "C" void kernel_launch(void* const* d_in, const int* in_sizes, int n_in,
                              void* d_out, int out_size, void* d_ws, size_t ws_size,
                              hipStream_t stream) {
    const float* x    = (const float*)d_in[0];
    const float* ctx  = (const float*)d_in[1];
    const float* Wq   = (const float*)d_in[2];
    const float* bq   = (const float*)d_in[3];
    const float* Wkv  = (const float*)d_in[4];
    const float* bkv  = (const float*)d_in[5];
    const float* Wo   = (const float*)d_in[6];
    const float* bo   = (const float*)d_in[7];
    const float* g1   = (const float*)d_in[8];
    const float* b1   = (const float*)d_in[9];
    const float* W1   = (const float*)d_in[10];
    const float* bf1  = (const float*)d_in[11];
    const float* W2   = (const float*)d_in[12];
    const float* bf2  = (const float*)d_in[13];
    const float* g2   = (const float*)d_in[14];
    const float* b2   = (const float*)d_in[15];

    char* ws = (char*)d_ws;
    const size_t MB = 1u << 20;
    ushort* XCb  = (ushort*)(ws + 0);        // [4096][1024] bf16 (8MB); later y2 f32
    ushort* WoT  = (ushort*)(ws + 8 * MB);   // 2MB
    ushort* W1T  = (ushort*)(ws + 10 * MB);  // 8MB
    ushort* W2T  = (ushort*)(ws + 18 * MB);  // 8MB
    ushort* WqT  = (ushort*)(ws + 26 * MB);  // 2MB; later x1b region
    ushort* WkvT = (ushort*)(ws + 28 * MB);  // 4MB
    ushort* Qs   = (ushort*)(ws + 32 * MB);  // 4MB; later x1f region
    ushort* attn = (ushort*)(ws + 36 * MB);  // 4MB
    ushort* KV   = (ushort*)(ws + 40 * MB);  // 16MB; later ff region
    ushort* Vt   = (ushort*)(ws + 56 * MB);  // 8MB; later y1 region
    ushort* x1b  = (ushort*)(ws + 26 * MB);  // 4MB (over WqT+WkvT)
    float*  x1f  = (float*)(ws + 32 * MB);   // 8MB (over Qs+attn)
    ushort* ffb  = (ushort*)(ws + 40 * MB);  // 16MB (over KV)
    float*  y1   = (float*)(ws + 56 * MB);   // 8MB (over Vt)
    float*  y2   = (float*)(ws + 0);         // 8MB (over XCb)

    // 1. convert activations
    cvt4<<<2048, 256, 0, stream>>>(x, XCb, 2048 * 1024);
    cvt4<<<2048, 256, 0, stream>>>(ctx, XCb + 2048 * 1024, 2048 * 1024);
    // 2. transpose+convert weights to [N][K] bf16
    tcvt<<<dim3(32, 32), dim3(32, 8), 0, stream>>>(Wq, WqT, 1024, 1024);
    tcvt<<<dim3(64, 32), dim3(32, 8), 0, stream>>>(Wkv, WkvT, 1024, 2048);
    tcvt<<<dim3(32, 32), dim3(32, 8), 0, stream>>>(Wo, WoT, 1024, 1024);
    tcvt<<<dim3(128, 32), dim3(32, 8), 0, stream>>>(W1, W1T, 1024, 4096);
    tcvt<<<dim3(32, 128), dim3(32, 8), 0, stream>>>(W2, W2T, 4096, 1024);
    // 3. Q = (x@Wq + bq) * 0.125  -> bf16
    gemm_bt<64, 128, 0, 0, 0, 1><<<dim3(8, 32), 256, 0, stream>>>(
        XCb, WqT, bq, nullptr, Qs, 2048, 1024, 1024, 0.125f);
    // 4. KV = [x;ctx]@Wkv + bkv -> bf16 [4096][2048]
    gemm_bt<128, 128, 0, 0, 0, 0><<<dim3(16, 32), 256, 0, stream>>>(
        XCb, WkvT, bkv, nullptr, KV, 4096, 2048, 1024, 1.f);
    // 5. Vt[d][j] = V[j][d]
    vtrans<<<dim3(128, 32), dim3(32, 8), 0, stream>>>(KV, Vt);
    // 6. attention -> bf16 [2048][1024]
    flash_attn<<<dim3(32, 16), 256, 0, stream>>>(Qs, KV, Vt, attn);
    // 7. y1 = attn@Wo + bo + x  (f32)
    gemm_bt<64, 128, 0, 1, 1, 0><<<dim3(8, 32), 256, 0, stream>>>(
        attn, WoT, bo, x, y1, 2048, 1024, 1024, 1.f);
    // 8. x1 = LN(y1) -> f32 + bf16
    layernorm_k<<<2048, 256, 0, stream>>>(y1, g1, b1, x1f, x1b);
    // 9. ff = gelu(x1@W1 + bf1) -> bf16 [2048][4096]
    gemm_bt<128, 128, 1, 0, 0, 0><<<dim3(32, 16), 256, 0, stream>>>(
        x1b, W1T, bf1, nullptr, ffb, 2048, 4096, 1024, 1.f);
    // 10. y2 = ff@W2 + bf2 + x1 (f32)
    gemm_bt<64, 128, 0, 1, 1, 0><<<dim3(8, 32), 256, 0, stream>>>(
        ffb, W2T, bf2, x1f, y2, 2048, 1024, 4096, 1.f);
    // 11. out = LN(y2) -> f32
    layernorm_k<<<2048, 256, 0, stream>>>(y2, g2, b2, (float*)d_out, nullptr);
}

// Round 2
// 285.971 us; speedup vs baseline: 1.0295x; 1.0295x over previous
//
#include <hip/hip_runtime.h>

// ---------------------------------------------------------------------------
// TransformerDecoderBlockV2: bf16 MFMA implementation for gfx950
// B=1, N=2048, M=2048, D=1024, H=16, dh=64, DFF=4096
// ---------------------------------------------------------------------------

using bf16x8 = __attribute__((ext_vector_type(8))) short;
using f32x4  = __attribute__((ext_vector_type(4))) float;

__device__ __forceinline__ ushort f2bf(float f) {
    unsigned u = __float_as_uint(f);
    unsigned r = (u + 0x7fffu + ((u >> 16) & 1u)) >> 16;
    return (ushort)r;
}

__device__ __forceinline__ void gload16(const void* g, void* l) {
    __builtin_amdgcn_global_load_lds(
        (const __attribute__((address_space(1))) void*)g,
        (__attribute__((address_space(3))) void*)l, 16, 0, 0);
}

__device__ __forceinline__ float gelu_erf(float v) {
    return 0.5f * v * (1.0f + erff(v * 0.70710678118654752f));
}

// ---------------------------------------------------------------------------
// f32 -> bf16 elementwise convert (vectorized, 4/thread)
// ---------------------------------------------------------------------------
__global__ __launch_bounds__(256) void cvt4(const float* __restrict__ in,
                                            ushort* __restrict__ out, int n) {
    int i = (blockIdx.x * 256 + threadIdx.x) * 4;
    if (i + 3 < n) {
        float4 v = *(const float4*)(in + i);
        ushort4 o;
        o.x = f2bf(v.x); o.y = f2bf(v.y); o.z = f2bf(v.z); o.w = f2bf(v.w);
        *(ushort4*)(out + i) = o;
    }
}

// ---------------------------------------------------------------------------
// Transpose + convert: in f32 [R][C]  ->  out bf16 [C][R]
// block (32,8), tile 32x32
// ---------------------------------------------------------------------------
__global__ __launch_bounds__(256) void tcvt(const float* __restrict__ in,
                                            ushort* __restrict__ out, int R, int C) {
    __shared__ float tile[32][33];
    const int tx = threadIdx.x, ty = threadIdx.y;
    const int c0 = blockIdx.x * 32, r0 = blockIdx.y * 32;
#pragma unroll
    for (int i = 0; i < 4; ++i)
        tile[ty + 8 * i][tx] = in[(size_t)(r0 + ty + 8 * i) * C + c0 + tx];
    __syncthreads();
#pragma unroll
    for (int i = 0; i < 4; ++i)
        out[(size_t)(c0 + ty + 8 * i) * R + r0 + tx] = f2bf(tile[tx][ty + 8 * i]);
}

// ---------------------------------------------------------------------------
// V transpose: KV bf16 [4096][2048] (V = cols 1024..2047) -> Vt bf16 [1024][4096]
// ---------------------------------------------------------------------------
__global__ __launch_bounds__(256) void vtrans(const ushort* __restrict__ KV,
                                              ushort* __restrict__ Vt) {
    __shared__ ushort tile[32][34];
    const int tx = threadIdx.x, ty = threadIdx.y;
    const int j0 = blockIdx.x * 32, d0 = blockIdx.y * 32;
#pragma unroll
    for (int i = 0; i < 4; ++i)
        tile[ty + 8 * i][tx] = KV[(size_t)(j0 + ty + 8 * i) * 2048 + 1024 + d0 + tx];
    __syncthreads();
#pragma unroll
    for (int i = 0; i < 4; ++i)
        Vt[(size_t)(d0 + ty + 8 * i) * 4096 + j0 + tx] = tile[tx][ty + 8 * i];
}

// ---------------------------------------------------------------------------
// GEMM: C[M][N] = epilogue( A[M][K]_bf16 * Bt[N][K]_bf16^T + bias )
// 4 waves in 2x2 grid over BMxBN tile, BK=64, 16x16x32 bf16 MFMA.
// LDS tiles XOR-swizzled: LDS[r][cb^((r&7)<<4)] holds global [r][cb].
// Staged via global_load_lds width 16 with pre-swizzled global source.
// ---------------------------------------------------------------------------
template <int BM, int BN, int ACT, int OUTF32, int RES, int SCALED>
__global__ __launch_bounds__(256) void gemm_bt(
    const ushort* __restrict__ A, const ushort* __restrict__ Bt,
    const float* __restrict__ bias, const float* __restrict__ resid,
    void* __restrict__ Cout, int M, int N, int K, float scale) {
    constexpr int MR = BM / 32, NR = BN / 32;
    __shared__ __align__(16) ushort Asm[BM * 64];
    __shared__ __align__(16) ushort Bsm[BN * 64];
    const int tid = threadIdx.x;
    const int w = tid >> 6, lane = tid & 63, g = lane >> 4, i15 = lane & 15;
    const int wm = w >> 1, wn = w & 1;
    const int m0 = blockIdx.y * BM, n0 = blockIdx.x * BN;

    f32x4 acc[MR][NR] = {};

    for (int kt = 0; kt < K; kt += 64) {
        // stage A tile (BM x 64 bf16 = BM*128 bytes)
#pragma unroll
        for (int q = 0; q < BM / 32; ++q) {
            int off = (w * (BM / 32) + q) * 1024 + lane * 16;
            int r = off >> 7, cb = off & 127;
            int scb = cb ^ ((r & 7) << 4);
            const void* src = (const char*)A + ((size_t)(m0 + r) * K + kt) * 2 + scb;
            gload16(src, (char*)Asm + (w * (BM / 32) + q) * 1024);
        }
        // stage B tile (BN x 64)
#pragma unroll
        for (int q = 0; q < BN / 32; ++q) {
            int off = (w * (BN / 32) + q) * 1024 + lane * 16;
            int r = off >> 7, cb = off & 127;
            int scb = cb ^ ((r & 7) << 4);
            const void* src = (const char*)Bt + ((size_t)(n0 + r) * K + kt) * 2 + scb;
            gload16(src, (char*)Bsm + (w * (BN / 32) + q) * 1024);
        }
        __syncthreads();

#pragma unroll
        for (int kc = 0; kc < 2; ++kc) {
            bf16x8 af[MR], bfr[NR];
#pragma unroll
            for (int mi = 0; mi < MR; ++mi) {
                int r = wm * (BM / 2) + mi * 16 + i15;
                af[mi] = *(const bf16x8*)((const char*)Asm + r * 128 +
                                          ((kc * 64 + g * 16) ^ ((r & 7) << 4)));
            }
#pragma unroll
            for (int ni = 0; ni < NR; ++ni) {
                int r = wn * (BN / 2) + ni * 16 + i15;
                bfr[ni] = *(const bf16x8*)((const char*)Bsm + r * 128 +
                                           ((kc * 64 + g * 16) ^ ((r & 7) << 4)));
            }
#pragma unroll
            for (int mi = 0; mi < MR; ++mi)
#pragma unroll
                for (int ni = 0; ni < NR; ++ni)
                    acc[mi][ni] = __builtin_amdgcn_mfma_f32_16x16x32_bf16(
                        af[mi], bfr[ni], acc[mi][ni], 0, 0, 0);
        }
        __syncthreads();
    }

    // epilogue: C/D layout col = lane&15, row = (lane>>4)*4 + reg
#pragma unroll
    for (int ni = 0; ni < NR; ++ni) {
        int col = n0 + wn * (BN / 2) + ni * 16 + i15;
        float bb = bias[col];
#pragma unroll
        for (int mi = 0; mi < MR; ++mi) {
#pragma unroll
            for (int r2 = 0; r2 < 4; ++r2) {
                int row = m0 + wm * (BM / 2) + mi * 16 + 4 * g + r2;
                float v = acc[mi][ni][r2] + bb;
                if (ACT) v = gelu_erf(v);
                if (SCALED) v *= scale;
                size_t off = (size_t)row * N + col;
                if (OUTF32) {
                    float rv = RES ? resid[off] : 0.f;
                    ((float*)Cout)[off] = v + rv;
                } else {
                    ((ushort*)Cout)[off] = f2bf(v);
                }
            }
        }
    }
}

// ---------------------------------------------------------------------------
// Flash attention v2 (swapped-QK^T), 4 waves x 16 q-rows, KVBLK=64.
// Q pre-scaled by dh^-0.5 * log2(e)  (softmax done in exp2 space — exact).
// Double-buffered K/V LDS, register-staged prefetch, ONE barrier per tile.
// Defer-max (THR=8). 1D grid: bid = q*16 + h so same-head blocks share an XCD.
// ---------------------------------------------------------------------------
__global__ __launch_bounds__(256) void flash_attn(
    const ushort* __restrict__ Q,    // [2048][1024] bf16 (pre-scaled)
    const ushort* __restrict__ KVb,  // [4096][2048] bf16 (K = cols 0..1023)
    const ushort* __restrict__ Vt,   // [1024][4096] bf16
    ushort* __restrict__ O) {        // [2048][1024] bf16
    constexpr int D = 1024;
    __shared__ __align__(16) ushort Ksm[2][64 * 64];   // [j][d] swizzled
    __shared__ __align__(16) ushort Vsm[2][64 * 64];   // [d][j] swizzled
    __shared__ __align__(16) ushort Psm[4][16][72];    // per-wave [i][j], row pad

    const int tid = threadIdx.x;
    const int w = tid >> 6, lane = tid & 63, g = lane >> 4, i15 = lane & 15;
    const int bid = blockIdx.x;
    const int h = bid & 15;                 // bid%8 == h%8 -> same-head same-XCD
    const int qi = 31 - (bid >> 4);         // heavy q-blocks first
    const int qb = qi * 64;
    const int qrow = qb + w * 16 + i15;

    bf16x8 qf[2];
    qf[0] = *(const bf16x8*)(Q + (size_t)qrow * D + h * 64 + g * 8);
    qf[1] = *(const bf16x8*)(Q + (size_t)qrow * D + h * 64 + 32 + g * 8);

    f32x4 o[4] = {};
    float m_run = -INFINITY, l_run = 0.f;

    const int diag = qi;
    const int ntiles = diag + 1 + 32;

    // staging geometry: 256 threads move a 64x64 bf16 tile in 2 rounds of 16B
    const int sr  = tid >> 3;               // rows 0..31 (and +32)
    const int scb = (tid & 7) * 16;         // byte col within 128B row
    const int ssw = scb ^ ((sr & 7) << 4);  // swizzled byte col ((r+32)&7 == r&7)
    const char* kb0 = (const char*)KVb + ((size_t)sr * 2048 + h * 64) * 2 + scb;
    const char* vb0 = (const char*)Vt + ((size_t)(h * 64 + sr) * 4096) * 2 + scb;

    uint4 kreg0, kreg1, vreg0, vreg1;
    auto stage = [&](int jt) {
        const char* kb = kb0 + (size_t)jt * 64 * 2048 * 2;
        kreg0 = *(const uint4*)kb;
        kreg1 = *(const uint4*)(kb + 32 * 2048 * 2);
        const char* vb = vb0 + (size_t)jt * 64 * 2;
        vreg0 = *(const uint4*)vb;
        vreg1 = *(const uint4*)(vb + 32 * 4096 * 2);
    };
    auto wlds = [&](int buf) {
        *(uint4*)((char*)Ksm[buf] + sr * 128 + ssw) = kreg0;
        *(uint4*)((char*)Ksm[buf] + (sr + 32) * 128 + ssw) = kreg1;
        *(uint4*)((char*)Vsm[buf] + sr * 128 + ssw) = vreg0;
        *(uint4*)((char*)Vsm[buf] + (sr + 32) * 128 + ssw) = vreg1;
    };

    stage(0);
    wlds(0);
    __syncthreads();
    int cur = 0;

    for (int t = 0; t < ntiles; ++t) {
        const int jt = (t <= diag) ? t : (32 + (t - diag - 1));
        const bool more = (t + 1 < ntiles);
        if (more) {
            const int jn = (t + 1 <= diag) ? (t + 1) : (32 + (t - diag));
            stage(jn);                       // global loads in flight over compute
        }

        // S^T = K * Q^T : lane holds col i=i15, rows j=jg*16+4g+r
        f32x4 st[4];
#pragma unroll
        for (int jg = 0; jg < 4; ++jg) {
            int jr = jg * 16 + i15;
            bf16x8 ka0 = *(const bf16x8*)((const char*)Ksm[cur] + jr * 128 +
                                          ((g * 16) ^ ((jr & 7) << 4)));
            bf16x8 ka1 = *(const bf16x8*)((const char*)Ksm[cur] + jr * 128 +
                                          ((64 + g * 16) ^ ((jr & 7) << 4)));
            f32x4 z = {};
            z = __builtin_amdgcn_mfma_f32_16x16x32_bf16(ka0, qf[0], z, 0, 0, 0);
            z = __builtin_amdgcn_mfma_f32_16x16x32_bf16(ka1, qf[1], z, 0, 0, 0);
            st[jg] = z;
        }
        if (jt == diag) {
#pragma unroll
            for (int jg = 0; jg < 4; ++jg)
#pragma unroll
                for (int r = 0; r < 4; ++r) {
                    int j = jt * 64 + jg * 16 + 4 * g + r;
                    if (j > qrow) st[jg][r] = -50000.f;
                }
        }

        // online softmax (exp2 space), row stats for i=i15
        float mt = -INFINITY;
#pragma unroll
        for (int jg = 0; jg < 4; ++jg)
#pragma unroll
            for (int r = 0; r < 4; ++r) mt = fmaxf(mt, st[jg][r]);
        mt = fmaxf(mt, __shfl_xor(mt, 16));
        mt = fmaxf(mt, __shfl_xor(mt, 32));

        const bool skip = __all(mt - m_run <= 8.f);   // defer-max (T13)
        float mnew, fscale;
        if (skip) { mnew = m_run; fscale = 1.f; }
        else      { mnew = fmaxf(m_run, mt); fscale = exp2f(m_run - mnew); }

        float psum = 0.f;
        ushort pb[4][4];
#pragma unroll
        for (int jg = 0; jg < 4; ++jg)
#pragma unroll
            for (int r = 0; r < 4; ++r) {
                float p = exp2f(st[jg][r] - mnew);
                psum += p;
                pb[jg][r] = f2bf(p);
            }
        psum += __shfl_xor(psum, 16);
        psum += __shfl_xor(psum, 32);
        l_run = l_run * fscale + psum;
        m_run = mnew;

        if (!skip) {
#pragma unroll
            for (int r = 0; r < 4; ++r) {
                float fr = __shfl(fscale, 20 * g + r);   // lane 16g + (4g+r)
#pragma unroll
                for (int dg = 0; dg < 4; ++dg) o[dg][r] *= fr;
            }
        }

        // P (bf16) -> per-wave LDS [16 i][64 j]  (no block barrier needed)
#pragma unroll
        for (int jg = 0; jg < 4; ++jg) {
            uint2 pk;
            pk.x = (uint)pb[jg][0] | ((uint)pb[jg][1] << 16);
            pk.y = (uint)pb[jg][2] | ((uint)pb[jg][3] << 16);
            *(uint2*)((char*)&Psm[w][i15][0] + jg * 32 + 8 * g) = pk;
        }

        // O += P * V
#pragma unroll
        for (int jc = 0; jc < 2; ++jc) {
            bf16x8 pa = *(const bf16x8*)((const char*)&Psm[w][i15][0] + jc * 64 + g * 16);
#pragma unroll
            for (int dg = 0; dg < 4; ++dg) {
                int dr = dg * 16 + i15;
                bf16x8 vb = *(const bf16x8*)((const char*)Vsm[cur] + dr * 128 +
                                             ((jc * 64 + g * 16) ^ ((dr & 7) << 4)));
                o[dg] = __builtin_amdgcn_mfma_f32_16x16x32_bf16(pa, vb, o[dg], 0, 0, 0);
            }
        }

        if (more) wlds(cur ^ 1);             // write next tile (other buffer)
        __syncthreads();                     // ONE barrier per tile
        cur ^= 1;
    }

    // final normalize + write
#pragma unroll
    for (int r = 0; r < 4; ++r) {
        float lr = __shfl(l_run, 20 * g + r);
        float inv = 1.f / lr;
#pragma unroll
        for (int dg = 0; dg < 4; ++dg) {
            int row = qb + w * 16 + 4 * g + r;
            int col = h * 64 + dg * 16 + i15;
            O[(size_t)row * D + col] = f2bf(o[dg][r] * inv);
        }
    }
}

// ---------------------------------------------------------------------------
// LayerNorm over D=1024, one block per row; writes f32 and optional bf16
// ---------------------------------------------------------------------------
__global__ __launch_bounds__(256) void layernorm_k(
    const float* __restrict__ in, const float* __restrict__ gam,
    const float* __restrict__ bet, float* __restrict__ outf,
    ushort* __restrict__ outb) {
    const int row = blockIdx.x, tid = threadIdx.x;
    const float4 v = *(const float4*)(in + (size_t)row * 1024 + tid * 4);
    float s = v.x + v.y + v.z + v.w;
    float sq = v.x * v.x + v.y * v.y + v.z * v.z + v.w * v.w;
#pragma unroll
    for (int d = 1; d < 64; d <<= 1) {
        s += __shfl_xor(s, d);
        sq += __shfl_xor(sq, d);
    }
    __shared__ float red[8];
    const int w = tid >> 6;
    if ((tid & 63) == 0) { red[w] = s; red[4 + w] = sq; }
    __syncthreads();
    s = red[0] + red[1] + red[2] + red[3];
    sq = red[4] + red[5] + red[6] + red[7];
    const float mu = s * (1.f / 1024.f);
    const float rs = rsqrtf(sq * (1.f / 1024.f) - mu * mu + 1e-5f);
    const float4 gg = *(const float4*)(gam + tid * 4);
    const float4 bb = *(const float4*)(bet + tid * 4);
    float4 o;
    o.x = (v.x - mu) * rs * gg.x + bb.x;
    o.y = (v.y - mu) * rs * gg.y + bb.y;
    o.z = (v.z - mu) * rs * gg.z + bb.z;
    o.w = (v.w - mu) * rs * gg.w + bb.w;
    *(float4*)(outf + (size_t)row * 1024 + tid * 4) = o;
    if (outb) {
        ushort4 ob;
        ob.x = f2bf(o.x); ob.y = f2bf(o.y); ob.z = f2bf(o.z); ob.w = f2bf(o.w);
        *(ushort4*)(outb + (size_t)row * 1024 + tid * 4) = ob;
    }
}

// ---------------------------------------------------------------------------
extern "C" void kernel_launch(void* const* d_in, const int* in_sizes, int n_in,
                              void* d_out, int out_size, void* d_ws, size_t ws_size,
                              hipStream_t stream) {
    const float* x    = (const float*)d_in[0];
    const float* ctx  = (const float*)d_in[1];
    const float* Wq   = (const float*)d_in[2];
    const float* bq   = (const float*)d_in[3];
    const float* Wkv  = (const float*)d_in[4];
    const float* bkv  = (const float*)d_in[5];
    const float* Wo   = (const float*)d_in[6];
    const float* bo   = (const float*)d_in[7];
    const float* g1   = (const float*)d_in[8];
    const float* b1   = (const float*)d_in[9];
    const float* W1   = (const float*)d_in[10];
    const float* bf1  = (const float*)d_in[11];
    const float* W2   = (const float*)d_in[12];
    const float* bf2  = (const float*)d_in[13];
    const float* g2   = (const float*)d_in[14];
    const float* b2   = (const float*)d_in[15];

    char* ws = (char*)d_ws;
    const size_t MB = 1u << 20;
    ushort* XCb  = (ushort*)(ws + 0);        // [4096][1024] bf16 (8MB); later y2 f32
    ushort* WoT  = (ushort*)(ws + 8 * MB);   // 2MB
    ushort* W1T  = (ushort*)(ws + 10 * MB);  // 8MB
    ushort* W2T  = (ushort*)(ws + 18 * MB);  // 8MB
    ushort* WqT  = (ushort*)(ws + 26 * MB);  // 2MB; later x1b region
    ushort* WkvT = (ushort*)(ws + 28 * MB);  // 4MB
    ushort* Qs   = (ushort*)(ws + 32 * MB);  // 4MB; later x1f region
    ushort* attn = (ushort*)(ws + 36 * MB);  // 4MB
    ushort* KV   = (ushort*)(ws + 40 * MB);  // 16MB; later ff region
    ushort* Vt   = (ushort*)(ws + 56 * MB);  // 8MB; later y1 region
    ushort* x1b  = (ushort*)(ws + 26 * MB);  // 4MB (over WqT+WkvT)
    float*  x1f  = (float*)(ws + 32 * MB);   // 8MB (over Qs+attn)
    ushort* ffb  = (ushort*)(ws + 40 * MB);  // 16MB (over KV)
    float*  y1   = (float*)(ws + 56 * MB);   // 8MB (over Vt)
    float*  y2   = (float*)(ws + 0);         // 8MB (over XCb)

    // 1. convert activations
    cvt4<<<2048, 256, 0, stream>>>(x, XCb, 2048 * 1024);
    cvt4<<<2048, 256, 0, stream>>>(ctx, XCb + 2048 * 1024, 2048 * 1024);
    // 2. transpose+convert weights to [N][K] bf16
    tcvt<<<dim3(32, 32), dim3(32, 8), 0, stream>>>(Wq, WqT, 1024, 1024);
    tcvt<<<dim3(64, 32), dim3(32, 8), 0, stream>>>(Wkv, WkvT, 1024, 2048);
    tcvt<<<dim3(32, 32), dim3(32, 8), 0, stream>>>(Wo, WoT, 1024, 1024);
    tcvt<<<dim3(128, 32), dim3(32, 8), 0, stream>>>(W1, W1T, 1024, 4096);
    tcvt<<<dim3(32, 128), dim3(32, 8), 0, stream>>>(W2, W2T, 4096, 1024);
    // 3. Q = (x@Wq + bq) * 0.125 * log2(e)  -> bf16 (exp2-space softmax)
    gemm_bt<64, 128, 0, 0, 0, 1><<<dim3(8, 32), 256, 0, stream>>>(
        XCb, WqT, bq, nullptr, Qs, 2048, 1024, 1024, 0.18033688011112042f);
    // 4. KV = [x;ctx]@Wkv + bkv -> bf16 [4096][2048]
    gemm_bt<128, 128, 0, 0, 0, 0><<<dim3(16, 32), 256, 0, stream>>>(
        XCb, WkvT, bkv, nullptr, KV, 4096, 2048, 1024, 1.f);
    // 5. Vt[d][j] = V[j][d]
    vtrans<<<dim3(128, 32), dim3(32, 8), 0, stream>>>(KV, Vt);
    // 6. attention -> bf16 [2048][1024]
    flash_attn<<<512, 256, 0, stream>>>(Qs, KV, Vt, attn);
    // 7. y1 = attn@Wo + bo + x  (f32)
    gemm_bt<64, 128, 0, 1, 1, 0><<<dim3(8, 32), 256, 0, stream>>>(
        attn, WoT, bo, x, y1, 2048, 1024, 1024, 1.f);
    // 8. x1 = LN(y1) -> f32 + bf16
    layernorm_k<<<2048, 256, 0, stream>>>(y1, g1, b1, x1f, x1b);
    // 9. ff = gelu(x1@W1 + bf1) -> bf16 [2048][4096]
    gemm_bt<128, 128, 1, 0, 0, 0><<<dim3(32, 16), 256, 0, stream>>>(
        x1b, W1T, bf1, nullptr, ffb, 2048, 4096, 1024, 1.f);
    // 10. y2 = ff@W2 + bf2 + x1 (f32)
    gemm_bt<64, 128, 0, 1, 1, 0><<<dim3(8, 32), 256, 0, stream>>>(
        ffb, W2T, bf2, x1f, y2, 2048, 1024, 4096, 1.f);
    // 11. out = LN(y2) -> f32
    layernorm_k<<<2048, 256, 0, stream>>>(y2, g2, b2, (float*)d_out, nullptr);
}

// Round 3
// 236.757 us; speedup vs baseline: 1.2435x; 1.2079x over previous
//
#include <hip/hip_runtime.h>

// ---------------------------------------------------------------------------
// TransformerDecoderBlockV2: bf16 MFMA implementation for gfx950
// B=1, N=2048, M=2048, D=1024, H=16, dh=64, DFF=4096
// ---------------------------------------------------------------------------

using bf16x8 = __attribute__((ext_vector_type(8))) short;
using f32x4  = __attribute__((ext_vector_type(4))) float;

__device__ __forceinline__ ushort f2bf(float f) {
    unsigned u = __float_as_uint(f);
    unsigned r = (u + 0x7fffu + ((u >> 16) & 1u)) >> 16;
    return (ushort)r;
}

__device__ __forceinline__ void gload16(const void* g, void* l) {
    __builtin_amdgcn_global_load_lds(
        (const __attribute__((address_space(1))) void*)g,
        (__attribute__((address_space(3))) void*)l, 16, 0, 0);
}

__device__ __forceinline__ float gelu_erf(float v) {
    return 0.5f * v * (1.0f + erff(v * 0.70710678118654752f));
}

// ---------------------------------------------------------------------------
__global__ __launch_bounds__(256) void cvt4(const float* __restrict__ in,
                                            ushort* __restrict__ out, int n) {
    int i = (blockIdx.x * 256 + threadIdx.x) * 4;
    if (i + 3 < n) {
        float4 v = *(const float4*)(in + i);
        ushort4 o;
        o.x = f2bf(v.x); o.y = f2bf(v.y); o.z = f2bf(v.z); o.w = f2bf(v.w);
        *(ushort4*)(out + i) = o;
    }
}

// ---------------------------------------------------------------------------
__global__ __launch_bounds__(256) void tcvt(const float* __restrict__ in,
                                            ushort* __restrict__ out, int R, int C) {
    __shared__ float tile[32][33];
    const int tx = threadIdx.x, ty = threadIdx.y;
    const int c0 = blockIdx.x * 32, r0 = blockIdx.y * 32;
#pragma unroll
    for (int i = 0; i < 4; ++i)
        tile[ty + 8 * i][tx] = in[(size_t)(r0 + ty + 8 * i) * C + c0 + tx];
    __syncthreads();
#pragma unroll
    for (int i = 0; i < 4; ++i)
        out[(size_t)(c0 + ty + 8 * i) * R + r0 + tx] = f2bf(tile[tx][ty + 8 * i]);
}

// ---------------------------------------------------------------------------
__global__ __launch_bounds__(256) void vtrans(const ushort* __restrict__ KV,
                                              ushort* __restrict__ Vt) {
    __shared__ ushort tile[32][34];
    const int tx = threadIdx.x, ty = threadIdx.y;
    const int j0 = blockIdx.x * 32, d0 = blockIdx.y * 32;
#pragma unroll
    for (int i = 0; i < 4; ++i)
        tile[ty + 8 * i][tx] = KV[(size_t)(j0 + ty + 8 * i) * 2048 + 1024 + d0 + tx];
    __syncthreads();
#pragma unroll
    for (int i = 0; i < 4; ++i)
        Vt[(size_t)(d0 + ty + 8 * i) * 4096 + j0 + tx] = tile[tx][ty + 8 * i];
}

// ---------------------------------------------------------------------------
// GEMM: C[M][N] = epilogue( A[M][K] * Bt[N][K]^T + bias ), bf16 in.
// SPLITK: blockIdx.z selects K-half; raw f32 partial out (bias via combine).
// ---------------------------------------------------------------------------
template <int BM, int BN, int ACT, int OUTF32, int RES, int SCALED, int SPLITK>
__global__ __launch_bounds__(256) void gemm_bt(
    const ushort* __restrict__ A, int lda, const ushort* __restrict__ Bt, int ldb,
    const float* __restrict__ bias, const float* __restrict__ resid,
    void* __restrict__ Cout, int M, int N, int K, float scale) {
    constexpr int MR = BM / 32, NR = BN / 32;
    __shared__ __align__(16) ushort Asm[BM * 64];
    __shared__ __align__(16) ushort Bsm[BN * 64];
    const int tid = threadIdx.x;
    const int w = tid >> 6, lane = tid & 63, g = lane >> 4, i15 = lane & 15;
    const int wm = w >> 1, wn = w & 1;
    const int m0 = blockIdx.y * BM, n0 = blockIdx.x * BN;
    if (SPLITK) {
        A += (size_t)blockIdx.z * K;
        Bt += (size_t)blockIdx.z * K;
    }

    f32x4 acc[MR][NR] = {};

    for (int kt = 0; kt < K; kt += 64) {
#pragma unroll
        for (int q = 0; q < BM / 32; ++q) {
            int off = (w * (BM / 32) + q) * 1024 + lane * 16;
            int r = off >> 7, cb = off & 127;
            int scb = cb ^ ((r & 7) << 4);
            const void* src = (const char*)A + ((size_t)(m0 + r) * lda + kt) * 2 + scb;
            gload16(src, (char*)Asm + (w * (BM / 32) + q) * 1024);
        }
#pragma unroll
        for (int q = 0; q < BN / 32; ++q) {
            int off = (w * (BN / 32) + q) * 1024 + lane * 16;
            int r = off >> 7, cb = off & 127;
            int scb = cb ^ ((r & 7) << 4);
            const void* src = (const char*)Bt + ((size_t)(n0 + r) * ldb + kt) * 2 + scb;
            gload16(src, (char*)Bsm + (w * (BN / 32) + q) * 1024);
        }
        __syncthreads();

#pragma unroll
        for (int kc = 0; kc < 2; ++kc) {
            bf16x8 af[MR], bfr[NR];
#pragma unroll
            for (int mi = 0; mi < MR; ++mi) {
                int r = wm * (BM / 2) + mi * 16 + i15;
                af[mi] = *(const bf16x8*)((const char*)Asm + r * 128 +
                                          ((kc * 64 + g * 16) ^ ((r & 7) << 4)));
            }
#pragma unroll
            for (int ni = 0; ni < NR; ++ni) {
                int r = wn * (BN / 2) + ni * 16 + i15;
                bfr[ni] = *(const bf16x8*)((const char*)Bsm + r * 128 +
                                           ((kc * 64 + g * 16) ^ ((r & 7) << 4)));
            }
#pragma unroll
            for (int mi = 0; mi < MR; ++mi)
#pragma unroll
                for (int ni = 0; ni < NR; ++ni)
                    acc[mi][ni] = __builtin_amdgcn_mfma_f32_16x16x32_bf16(
                        af[mi], bfr[ni], acc[mi][ni], 0, 0, 0);
        }
        __syncthreads();
    }

    float* Cf = (float*)Cout;
    if (SPLITK) Cf += (size_t)blockIdx.z * M * N;

#pragma unroll
    for (int ni = 0; ni < NR; ++ni) {
        int col = n0 + wn * (BN / 2) + ni * 16 + i15;
        float bb = bias ? bias[col] : 0.f;
#pragma unroll
        for (int mi = 0; mi < MR; ++mi) {
#pragma unroll
            for (int r2 = 0; r2 < 4; ++r2) {
                int row = m0 + wm * (BM / 2) + mi * 16 + 4 * g + r2;
                float v = acc[mi][ni][r2] + bb;
                if (ACT) v = gelu_erf(v);
                if (SCALED) v *= scale;
                size_t off = (size_t)row * N + col;
                if (OUTF32) {
                    float rv = RES ? resid[off] : 0.f;
                    Cf[off] = v + rv;
                } else {
                    ((ushort*)Cout)[off] = f2bf(v);
                }
            }
        }
    }
}

// ---------------------------------------------------------------------------
// Flash attention (swapped-QK^T), 4 waves x 16 q-rows, KVBLK=64, exp2 space.
// Double-buffered K/V LDS, register prefetch, 1 barrier/tile, defer-max.
// SPLIT=1: KV range split in 2 (grid z-doubling via bid); writes unnormalized
// f32 partials + (m,l); combined by attn_combine. LDS = 40960 B (4 blocks/CU).
// ---------------------------------------------------------------------------
template <int SPLIT>
__global__ __launch_bounds__(256) void flash_attn(
    const ushort* __restrict__ Q,    // [2048][1024] bf16 (pre-scaled by 0.125*log2e)
    const ushort* __restrict__ KVb,  // [4096][2048] bf16 (K = cols 0..1023)
    const ushort* __restrict__ Vt,   // [1024][4096] bf16
    ushort* __restrict__ O,          // [2048][1024] bf16 (SPLIT=0)
    float* __restrict__ Opart,       // [2][2048][1024] f32 (SPLIT=1)
    float* __restrict__ Ml) {        // [2][2048][16][2] f32 (SPLIT=1)
    constexpr int D = 1024;
    __shared__ __align__(16) ushort Ksm[2][64 * 64];
    __shared__ __align__(16) ushort Vsm[2][64 * 64];
    __shared__ __align__(16) ushort Psm[4][16 * 64];   // per-wave, XOR-swizzled

    const int tid = threadIdx.x;
    const int w = tid >> 6, lane = tid & 63, g = lane >> 4, i15 = lane & 15;
    const int bid = blockIdx.x;
    const int h = bid & 15;                 // bid%8 == h%8 -> same-head same-XCD
    int qi, s;
    if (SPLIT) { qi = 31 - ((bid >> 4) >> 1); s = (bid >> 4) & 1; }
    else       { qi = 31 - (bid >> 4); s = 0; }
    const int qb = qi * 64;
    const int qrow = qb + w * 16 + i15;

    bf16x8 qf[2];
    qf[0] = *(const bf16x8*)(Q + (size_t)qrow * D + h * 64 + g * 8);
    qf[1] = *(const bf16x8*)(Q + (size_t)qrow * D + h * 64 + 32 + g * 8);

    f32x4 o[4] = {};
    float m_run = -INFINITY, l_run = 0.f;

    const int diag = qi;
    const int nt = diag + 33;
    const int lo = (SPLIT && s) ? (nt >> 1) : 0;
    const int hi = SPLIT ? (s ? nt : (nt >> 1)) : nt;

    const int sr  = tid >> 3;               // rows 0..31 (and +32)
    const int scb = (tid & 7) * 16;
    const int ssw = scb ^ ((sr & 7) << 4);
    const char* kb0 = (const char*)KVb + ((size_t)sr * 2048 + h * 64) * 2 + scb;
    const char* vb0 = (const char*)Vt + ((size_t)(h * 64 + sr) * 4096) * 2 + scb;

    uint4 kreg0, kreg1, vreg0, vreg1;
    auto jt_of = [&](int t) { return (t <= diag) ? t : (32 + (t - diag - 1)); };
    auto stage = [&](int jt) {
        const char* kb = kb0 + (size_t)jt * 64 * 2048 * 2;
        kreg0 = *(const uint4*)kb;
        kreg1 = *(const uint4*)(kb + 32 * 2048 * 2);
        const char* vb = vb0 + (size_t)jt * 64 * 2;
        vreg0 = *(const uint4*)vb;
        vreg1 = *(const uint4*)(vb + 32 * 4096 * 2);
    };
    auto wlds = [&](int buf) {
        *(uint4*)((char*)Ksm[buf] + sr * 128 + ssw) = kreg0;
        *(uint4*)((char*)Ksm[buf] + (sr + 32) * 128 + ssw) = kreg1;
        *(uint4*)((char*)Vsm[buf] + sr * 128 + ssw) = vreg0;
        *(uint4*)((char*)Vsm[buf] + (sr + 32) * 128 + ssw) = vreg1;
    };

    stage(jt_of(lo));
    wlds(0);
    __syncthreads();
    int cur = 0;

    const int pbase = i15 * 128;            // within Psm[w]
    const int psw = (i15 & 7) << 4;

    for (int t = lo; t < hi; ++t) {
        const int jt = jt_of(t);
        const bool more = (t + 1 < hi);
        if (more) stage(jt_of(t + 1));

        // S^T = K * Q^T
        f32x4 st[4];
#pragma unroll
        for (int jg = 0; jg < 4; ++jg) {
            int jr = jg * 16 + i15;
            bf16x8 ka0 = *(const bf16x8*)((const char*)Ksm[cur] + jr * 128 +
                                          ((g * 16) ^ ((jr & 7) << 4)));
            bf16x8 ka1 = *(const bf16x8*)((const char*)Ksm[cur] + jr * 128 +
                                          ((64 + g * 16) ^ ((jr & 7) << 4)));
            f32x4 z = {};
            z = __builtin_amdgcn_mfma_f32_16x16x32_bf16(ka0, qf[0], z, 0, 0, 0);
            z = __builtin_amdgcn_mfma_f32_16x16x32_bf16(ka1, qf[1], z, 0, 0, 0);
            st[jg] = z;
        }
        if (jt == diag) {
#pragma unroll
            for (int jg = 0; jg < 4; ++jg)
#pragma unroll
                for (int r = 0; r < 4; ++r) {
                    int j = jt * 64 + jg * 16 + 4 * g + r;
                    if (j > qrow) st[jg][r] = -50000.f;
                }
        }

        // online softmax (exp2 space)
        float mt = -INFINITY;
#pragma unroll
        for (int jg = 0; jg < 4; ++jg)
#pragma unroll
            for (int r = 0; r < 4; ++r) mt = fmaxf(mt, st[jg][r]);
        mt = fmaxf(mt, __shfl_xor(mt, 16));
        mt = fmaxf(mt, __shfl_xor(mt, 32));

        const bool skip = __all(mt - m_run <= 8.f);
        float mnew, fscale;
        if (skip) { mnew = m_run; fscale = 1.f; }
        else      { mnew = fmaxf(m_run, mt); fscale = exp2f(m_run - mnew); }

        float psum = 0.f;
        float pf[4][4];
#pragma unroll
        for (int jg = 0; jg < 4; ++jg)
#pragma unroll
            for (int r = 0; r < 4; ++r) {
                float p = exp2f(st[jg][r] - mnew);
                psum += p;
                pf[jg][r] = p;
            }
        psum += __shfl_xor(psum, 16);
        psum += __shfl_xor(psum, 32);
        l_run = l_run * fscale + psum;
        m_run = mnew;

        if (!skip) {
#pragma unroll
            for (int r = 0; r < 4; ++r) {
                float fr = __shfl(fscale, 20 * g + r);
#pragma unroll
                for (int dg = 0; dg < 4; ++dg) o[dg][r] *= fr;
            }
        }

        // pack P (v_cvt_pk_bf16_f32, RNE) -> per-wave swizzled LDS [16 i][64 j]
#pragma unroll
        for (int jg = 0; jg < 4; ++jg) {
            uint pk0, pk1;
            asm("v_cvt_pk_bf16_f32 %0, %1, %2" : "=v"(pk0) : "v"(pf[jg][0]), "v"(pf[jg][1]));
            asm("v_cvt_pk_bf16_f32 %0, %1, %2" : "=v"(pk1) : "v"(pf[jg][2]), "v"(pf[jg][3]));
            uint2 pk; pk.x = pk0; pk.y = pk1;
            *(uint2*)((char*)Psm[w] + pbase + ((jg * 32 + g * 8) ^ psw)) = pk;
        }

        // O += P * V
#pragma unroll
        for (int jc = 0; jc < 2; ++jc) {
            bf16x8 pa = *(const bf16x8*)((const char*)Psm[w] + pbase +
                                         ((jc * 64 + g * 16) ^ psw));
#pragma unroll
            for (int dg = 0; dg < 4; ++dg) {
                int dr = dg * 16 + i15;
                bf16x8 vb = *(const bf16x8*)((const char*)Vsm[cur] + dr * 128 +
                                             ((jc * 64 + g * 16) ^ ((dr & 7) << 4)));
                o[dg] = __builtin_amdgcn_mfma_f32_16x16x32_bf16(pa, vb, o[dg], 0, 0, 0);
            }
        }

        if (more) wlds(cur ^ 1);
        __syncthreads();
        cur ^= 1;
    }

    if (SPLIT) {
        if (g == 0) {
            float* mp = Ml + ((size_t)(s * 2048 + qb + w * 16 + i15) * 16 + h) * 2;
            mp[0] = m_run; mp[1] = l_run;
        }
#pragma unroll
        for (int r = 0; r < 4; ++r)
#pragma unroll
            for (int dg = 0; dg < 4; ++dg) {
                int row = qb + w * 16 + 4 * g + r;
                int col = h * 64 + dg * 16 + i15;
                Opart[(size_t)(s * 2048 + row) * 1024 + col] = o[dg][r];
            }
    } else {
#pragma unroll
        for (int r = 0; r < 4; ++r) {
            float lr = __shfl(l_run, 20 * g + r);
            float inv = 1.f / lr;
#pragma unroll
            for (int dg = 0; dg < 4; ++dg) {
                int row = qb + w * 16 + 4 * g + r;
                int col = h * 64 + dg * 16 + i15;
                O[(size_t)row * D + col] = f2bf(o[dg][r] * inv);
            }
        }
    }
}

// ---------------------------------------------------------------------------
__global__ __launch_bounds__(256) void attn_combine(
    const float* __restrict__ Opart, const float* __restrict__ Ml,
    ushort* __restrict__ O) {
    const int row = blockIdx.x, tid = threadIdx.x;
    const int c = tid * 4, h = c >> 6;
    const float* mp0 = Ml + ((size_t)row * 16 + h) * 2;
    const float* mp1 = Ml + ((size_t)(2048 + row) * 16 + h) * 2;
    float m0 = mp0[0], l0 = mp0[1], m1 = mp1[0], l1 = mp1[1];
    float m = fmaxf(m0, m1);
    float w0 = exp2f(m0 - m), w1 = exp2f(m1 - m);
    float inv = 1.f / (l0 * w0 + l1 * w1);
    float4 a = *(const float4*)(Opart + (size_t)row * 1024 + c);
    float4 b = *(const float4*)(Opart + (size_t)(2048 + row) * 1024 + c);
    ushort4 ob;
    ob.x = f2bf((a.x * w0 + b.x * w1) * inv);
    ob.y = f2bf((a.y * w0 + b.y * w1) * inv);
    ob.z = f2bf((a.z * w0 + b.z * w1) * inv);
    ob.w = f2bf((a.w * w0 + b.w * w1) * inv);
    *(ushort4*)(O + (size_t)row * 1024 + c) = ob;
}

// ---------------------------------------------------------------------------
// LayerNorm over D=1024, one block/row; optional bf16 copy out
// ---------------------------------------------------------------------------
__global__ __launch_bounds__(256) void layernorm_k(
    const float* __restrict__ in, const float* __restrict__ gam,
    const float* __restrict__ bet, float* __restrict__ outf,
    ushort* __restrict__ outb) {
    const int row = blockIdx.x, tid = threadIdx.x;
    const float4 v = *(const float4*)(in + (size_t)row * 1024 + tid * 4);
    float s = v.x + v.y + v.z + v.w;
    float sq = v.x * v.x + v.y * v.y + v.z * v.z + v.w * v.w;
#pragma unroll
    for (int d = 1; d < 64; d <<= 1) {
        s += __shfl_xor(s, d);
        sq += __shfl_xor(sq, d);
    }
    __shared__ float red[8];
    const int w = tid >> 6;
    if ((tid & 63) == 0) { red[w] = s; red[4 + w] = sq; }
    __syncthreads();
    s = red[0] + red[1] + red[2] + red[3];
    sq = red[4] + red[5] + red[6] + red[7];
    const float mu = s * (1.f / 1024.f);
    const float rs = rsqrtf(sq * (1.f / 1024.f) - mu * mu + 1e-5f);
    const float4 gg = *(const float4*)(gam + tid * 4);
    const float4 bb = *(const float4*)(bet + tid * 4);
    float4 o;
    o.x = (v.x - mu) * rs * gg.x + bb.x;
    o.y = (v.y - mu) * rs * gg.y + bb.y;
    o.z = (v.z - mu) * rs * gg.z + bb.z;
    o.w = (v.w - mu) * rs * gg.w + bb.w;
    *(float4*)(outf + (size_t)row * 1024 + tid * 4) = o;
    if (outb) {
        ushort4 ob;
        ob.x = f2bf(o.x); ob.y = f2bf(o.y); ob.z = f2bf(o.z); ob.w = f2bf(o.w);
        *(ushort4*)(outb + (size_t)row * 1024 + tid * 4) = ob;
    }
}

// ---------------------------------------------------------------------------
// Final LN over (P0 + P1 + bias + resid)  (FFN2 split-K merge fused in)
// ---------------------------------------------------------------------------
__global__ __launch_bounds__(256) void layernorm_comb(
    const float* __restrict__ in0, const float* __restrict__ in1,
    const float* __restrict__ bias, const float* __restrict__ resid,
    const float* __restrict__ gam, const float* __restrict__ bet,
    float* __restrict__ outf) {
    const int row = blockIdx.x, tid = threadIdx.x;
    const float4 a = *(const float4*)(in0 + (size_t)row * 1024 + tid * 4);
    const float4 b = *(const float4*)(in1 + (size_t)row * 1024 + tid * 4);
    const float4 rr = *(const float4*)(resid + (size_t)row * 1024 + tid * 4);
    const float4 bs = *(const float4*)(bias + tid * 4);
    float4 v;
    v.x = a.x + b.x + rr.x + bs.x;
    v.y = a.y + b.y + rr.y + bs.y;
    v.z = a.z + b.z + rr.z + bs.z;
    v.w = a.w + b.w + rr.w + bs.w;
    float s = v.x + v.y + v.z + v.w;
    float sq = v.x * v.x + v.y * v.y + v.z * v.z + v.w * v.w;
#pragma unroll
    for (int d = 1; d < 64; d <<= 1) {
        s += __shfl_xor(s, d);
        sq += __shfl_xor(sq, d);
    }
    __shared__ float red[8];
    const int w = tid >> 6;
    if ((tid & 63) == 0) { red[w] = s; red[4 + w] = sq; }
    __syncthreads();
    s = red[0] + red[1] + red[2] + red[3];
    sq = red[4] + red[5] + red[6] + red[7];
    const float mu = s * (1.f / 1024.f);
    const float rs = rsqrtf(sq * (1.f / 1024.f) - mu * mu + 1e-5f);
    const float4 gg = *(const float4*)(gam + tid * 4);
    const float4 bb = *(const float4*)(bet + tid * 4);
    float4 o;
    o.x = (v.x - mu) * rs * gg.x + bb.x;
    o.y = (v.y - mu) * rs * gg.y + bb.y;
    o.z = (v.z - mu) * rs * gg.z + bb.z;
    o.w = (v.w - mu) * rs * gg.w + bb.w;
    *(float4*)(outf + (size_t)row * 1024 + tid * 4) = o;
}

// ---------------------------------------------------------------------------
extern "C" void kernel_launch(void* const* d_in, const int* in_sizes, int n_in,
                              void* d_out, int out_size, void* d_ws, size_t ws_size,
                              hipStream_t stream) {
    const float* x    = (const float*)d_in[0];
    const float* ctx  = (const float*)d_in[1];
    const float* Wq   = (const float*)d_in[2];
    const float* bq   = (const float*)d_in[3];
    const float* Wkv  = (const float*)d_in[4];
    const float* bkv  = (const float*)d_in[5];
    const float* Wo   = (const float*)d_in[6];
    const float* bo   = (const float*)d_in[7];
    const float* g1   = (const float*)d_in[8];
    const float* b1   = (const float*)d_in[9];
    const float* W1   = (const float*)d_in[10];
    const float* bf1  = (const float*)d_in[11];
    const float* W2   = (const float*)d_in[12];
    const float* bf2  = (const float*)d_in[13];
    const float* g2   = (const float*)d_in[14];
    const float* b2   = (const float*)d_in[15];

    char* ws = (char*)d_ws;
    const size_t MB = 1u << 20;
    ushort* XCb  = (ushort*)(ws + 0);        // 8MB; later FFN2 partials P0/P1
    ushort* WoT  = (ushort*)(ws + 8 * MB);   // 2MB
    ushort* W1T  = (ushort*)(ws + 10 * MB);  // 8MB
    ushort* W2T  = (ushort*)(ws + 18 * MB);  // 8MB
    ushort* WqT  = (ushort*)(ws + 26 * MB);  // 2MB; later x1b
    ushort* WkvT = (ushort*)(ws + 28 * MB);  // 4MB
    ushort* Qs   = (ushort*)(ws + 32 * MB);  // 4MB; later x1f
    ushort* attn = (ushort*)(ws + 36 * MB);  // 4MB
    ushort* KV   = (ushort*)(ws + 40 * MB);  // 16MB; later ff
    ushort* Vt   = (ushort*)(ws + 56 * MB);  // 8MB; later y1
    ushort* x1b  = (ushort*)(ws + 26 * MB);  // 4MB
    float*  x1f  = (float*)(ws + 32 * MB);   // 8MB
    ushort* ffb  = (ushort*)(ws + 40 * MB);  // 16MB
    float*  y1   = (float*)(ws + 56 * MB);   // 8MB
    float*  Pk   = (float*)(ws + 0);         // 16MB: FFN2 split-K partials
    float*  Opart = (float*)(ws + 64 * MB);  // 16MB: attn split partials
    float*  Ml    = (float*)(ws + 80 * MB);  // 512KB
    const bool split = ws_size >= 81 * MB;

    cvt4<<<2048, 256, 0, stream>>>(x, XCb, 2048 * 1024);
    cvt4<<<2048, 256, 0, stream>>>(ctx, XCb + 2048 * 1024, 2048 * 1024);
    tcvt<<<dim3(32, 32), dim3(32, 8), 0, stream>>>(Wq, WqT, 1024, 1024);
    tcvt<<<dim3(64, 32), dim3(32, 8), 0, stream>>>(Wkv, WkvT, 1024, 2048);
    tcvt<<<dim3(32, 32), dim3(32, 8), 0, stream>>>(Wo, WoT, 1024, 1024);
    tcvt<<<dim3(128, 32), dim3(32, 8), 0, stream>>>(W1, W1T, 1024, 4096);
    tcvt<<<dim3(32, 128), dim3(32, 8), 0, stream>>>(W2, W2T, 4096, 1024);
    // Q = (x@Wq + bq) * 0.125 * log2(e)
    gemm_bt<64, 128, 0, 0, 0, 1, 0><<<dim3(8, 32), 256, 0, stream>>>(
        XCb, 1024, WqT, 1024, bq, nullptr, Qs, 2048, 1024, 1024, 0.18033688011112042f);
    gemm_bt<128, 128, 0, 0, 0, 0, 0><<<dim3(16, 32), 256, 0, stream>>>(
        XCb, 1024, WkvT, 1024, bkv, nullptr, KV, 4096, 2048, 1024, 1.f);
    vtrans<<<dim3(128, 32), dim3(32, 8), 0, stream>>>(KV, Vt);
    if (split) {
        flash_attn<1><<<1024, 256, 0, stream>>>(Qs, KV, Vt, nullptr, Opart, Ml);
        attn_combine<<<2048, 256, 0, stream>>>(Opart, Ml, attn);
    } else {
        flash_attn<0><<<512, 256, 0, stream>>>(Qs, KV, Vt, attn, nullptr, nullptr);
    }
    gemm_bt<64, 128, 0, 1, 1, 0, 0><<<dim3(8, 32), 256, 0, stream>>>(
        attn, 1024, WoT, 1024, bo, x, y1, 2048, 1024, 1024, 1.f);
    layernorm_k<<<2048, 256, 0, stream>>>(y1, g1, b1, x1f, x1b);
    gemm_bt<128, 128, 1, 0, 0, 0, 0><<<dim3(32, 16), 256, 0, stream>>>(
        x1b, 1024, W1T, 1024, bf1, nullptr, ffb, 2048, 4096, 1024, 1.f);
    // FFN2 split-K x2 (concurrent via grid z), raw f32 partials
    gemm_bt<64, 128, 0, 1, 0, 0, 1><<<dim3(8, 32, 2), 256, 0, stream>>>(
        ffb, 4096, W2T, 4096, nullptr, nullptr, Pk, 2048, 1024, 2048, 1.f);
    // out = LN(P0 + P1 + bf2 + x1)
    layernorm_comb<<<2048, 256, 0, stream>>>(Pk, Pk + 2048 * 1024, bf2, x1f,
                                             g2, b2, (float*)d_out);
}